// Round 8
// baseline (91.259 us; speedup 1.0000x reference)
//
#include <hip/hip_runtime.h>
#include <hip/hip_bf16.h>

// Dynamic conv2d: B=16, C_in=64, H=W=128, C_out=64, K=5, ks=3, pad=1.
// R8: 16x16x32 MFMA variant of the streaming conv. A per wave = 18 frags
// (72 VGPR) -> ~120 regs/thread -> 4 waves/SIMD -> 2 blocks/CU co-resident.
// Latency hiding via TLP (other block), not ILP. R6 step structure kept.

typedef __attribute__((ext_vector_type(8))) __bf16 bf16x8;
typedef __attribute__((ext_vector_type(4))) float f32x4;
typedef __attribute__((ext_vector_type(4))) unsigned int u32x4;

#define NB 16
#define CI 64
#define CO 64
#define HH 128
#define WW 128
#define KBANK 5
#define ASTR 36864            // shorts of aggw per b: 4m * 18ks * 64lane * 8j

__device__ __forceinline__ unsigned short f2bfu(float f) {
    __hip_bfloat16 h = __float2bfloat16(f);
    unsigned short s;
    __builtin_memcpy(&s, &h, 2);
    return s;
}

// ---------------- kernel 1: aggregate weights + bias ----------------
// aggw per b: [m(4)][ks(18)][lane(64)][j(8)]:
//   co = m*16 + (lane&15), k = ks*32 + (lane>>4)*8 + j, tap = k>>6, ci = k&63.
// A wave-load (lane l, frag ks) = base + ks*512 + l*8 -> contiguous 1KB.
__global__ void prep_kernel(const float* __restrict__ weights,
                            const float* __restrict__ Wbank,
                            const float* __restrict__ bbank,
                            short* __restrict__ aggw,
                            float* __restrict__ aggb) {
    int idx = blockIdx.x * 256 + threadIdx.x;          // < 16*36864
    int b   = idx / ASTR;
    int rem = idx - b * ASTR;
    int j   = rem & 7;
    int l   = (rem >> 3) & 63;
    int mk  = rem >> 9;                // 0..71 = m*18 + ks
    int m   = mk / 18;
    int ks  = mk - m * 18;
    int co  = m * 16 + (l & 15);
    int k   = ks * 32 + (l >> 4) * 8 + j;
    int tap = k >> 6;
    int ci  = k & 63;
    float s = 0.f;
#pragma unroll
    for (int kk = 0; kk < KBANK; ++kk)
        s += weights[b * KBANK + kk] * Wbank[((kk * CO + co) * CI + ci) * 9 + tap];
    aggw[idx] = (short)f2bfu(s);
    if (k == 0) {
        float sb = 0.f;
#pragma unroll
        for (int kk = 0; kk < KBANK; ++kk)
            sb += weights[b * KBANK + kk] * bbank[kk * CO + co];
        aggb[b * CO + co] = sb;
    }
}

// ---------------- kernel 2: streaming conv ----------------
// ring[slot 4][ch 8][pix 130][8 shorts]; ch = ci>>3; pix = input w + 1.
__device__ __forceinline__ void load16(const float* __restrict__ xb, int r,
                                       int sw, int scg, float (&pv)[16]) {
#pragma unroll
    for (int i = 0; i < 16; ++i)
        pv[i] = xb[((size_t)(scg * 16 + i) * HH + r) * WW + sw];
}

__device__ __forceinline__ void write16(short* __restrict__ slot, int sw, int scg,
                                        const float (&pv)[16]) {
#pragma unroll
    for (int h = 0; h < 2; ++h) {
        unsigned u0 = (unsigned)f2bfu(pv[h * 8 + 0]) | ((unsigned)f2bfu(pv[h * 8 + 1]) << 16);
        unsigned u1 = (unsigned)f2bfu(pv[h * 8 + 2]) | ((unsigned)f2bfu(pv[h * 8 + 3]) << 16);
        unsigned u2 = (unsigned)f2bfu(pv[h * 8 + 4]) | ((unsigned)f2bfu(pv[h * 8 + 5]) << 16);
        unsigned u3 = (unsigned)f2bfu(pv[h * 8 + 6]) | ((unsigned)f2bfu(pv[h * 8 + 7]) << 16);
        *(u32x4*)&slot[((scg * 2 + h) * 130 + sw + 1) * 8] = u32x4{u0, u1, u2, u3};
    }
}

__global__ __launch_bounds__(512, 4) void conv_kernel(const float* __restrict__ x,
                                                      const short* __restrict__ aggw,
                                                      const float* __restrict__ aggb,
                                                      float* __restrict__ out) {
    __shared__ short ring[4][8][130][8];               // 66,560 B (2 blocks/CU)

    const int t   = threadIdx.x;
    const int lin = blockIdx.x;                        // 512 blocks
    const int b     = (lin & 7) * 2 + ((lin >> 3) & 1);// all strips of b on 1 XCD
    const int strip = lin >> 4;                        // 0..31
    const int r0    = strip * 4;

    const int l   = t & 63;
    const int wv  = t >> 6;        // 0..7
    const int m   = wv >> 1;       // co quarter (0..3)
    const int hh  = wv & 1;        // pix half
    const int ln  = l & 15;        // n-index within 16
    const int sub = l >> 4;        // k-subgroup / co-row group

    const int sw  = t & 127;       // staging: w
    const int scg = t >> 7;        // staging: 16-ci group

    const float* xb = x + (size_t)b * CI * HH * WW;
    const short* Ab = aggw + (size_t)b * ASTR + (size_t)m * 18 * 512;

    // A-quarter into registers: 18 x bf16x8 (72 VGPR), coalesced 1KB/wave
    bf16x8 A[18];
#pragma unroll
    for (int ks = 0; ks < 18; ++ks)
        A[ks] = *(const bf16x8*)(Ab + ks * 512 + l * 8);

    // bias: 4 values (co = m*16 + sub*4 + reg)
    float bias[4];
#pragma unroll
    for (int rg = 0; rg < 4; ++rg)
        bias[rg] = aggb[b * CO + m * 16 + sub * 4 + rg];

    // zero pix-halo (pix 0 and 129) of all 4 slots
    if (t < 64) {
        int slot = t >> 4, ch = (t >> 1) & 7, px = (t & 1) * 129;
        *(u32x4*)&ring[slot][ch][px][0] = u32x4{0u, 0u, 0u, 0u};
    }

    // prologue: rows r0-1, r0, r0+1 -> slots 0,1,2
    {
        float p0[16], p1[16];
        if (r0 >= 1) load16(xb, r0 - 1, sw, scg, p0);
        else {
#pragma unroll
            for (int i = 0; i < 16; ++i) p0[i] = 0.f;
        }
        load16(xb, r0, sw, scg, p1);
        write16(&ring[0][0][0][0], sw, scg, p0);
        write16(&ring[1][0][0][0], sw, scg, p1);
        load16(xb, r0 + 1, sw, scg, p0);               // reuse p0 (ds_write drained it)
        write16(&ring[2][0][0][0], sw, scg, p0);
    }
    __syncthreads();

    // 4 row-steps
#pragma unroll
    for (int ri = 0; ri < 4; ++ri) {
        const int r = r0 + ri;

        // issue next x-row loads at step start (cover = MFMA phase)
        float pv[16];
#pragma unroll
        for (int i = 0; i < 16; ++i) pv[i] = 0.f;
        const bool stage = (ri < 3);
        if (stage && (r + 2 < 128)) load16(xb, r + 2, sw, scg, pv);

        f32x4 acc[4];
#pragma unroll
        for (int nt = 0; nt < 4; ++nt) acc[nt] = f32x4{0.f, 0.f, 0.f, 0.f};

#pragma unroll
        for (int tap = 0; tap < 9; ++tap) {
            const int dy = tap / 3, dx = tap - dy * 3;
            const short* sb = &ring[(ri + dy) & 3][0][0][0];
#pragma unroll
            for (int k2 = 0; k2 < 2; ++k2) {
                const int ch = k2 * 4 + sub;
#pragma unroll
                for (int nt = 0; nt < 4; ++nt) {
                    const int pix = hh * 64 + nt * 16 + ln + dx;   // ring pix = w+1
                    bf16x8 bv = *(const bf16x8*)&sb[(ch * 130 + pix) * 8];
                    acc[nt] = __builtin_amdgcn_mfma_f32_16x16x32_bf16(
                        A[tap * 2 + k2], bv, acc[nt], 0, 0, 0);
                }
            }
        }

        // stores: D col=lane&15 (pix), row=(lane>>4)*4+reg (co)
#pragma unroll
        for (int nt = 0; nt < 4; ++nt) {
            const int wc = hh * 64 + nt * 16 + ln;
#pragma unroll
            for (int rg = 0; rg < 4; ++rg) {
                int co = m * 16 + sub * 4 + rg;
                out[(((size_t)b * CO + co) * HH + r) * WW + wc] = acc[nt][rg] + bias[rg];
            }
        }

        if (stage) write16(&ring[(ri + 3) & 3][0][0][0], sw, scg, pv);
        __syncthreads();
    }
}

extern "C" void kernel_launch(void* const* d_in, const int* in_sizes, int n_in,
                              void* d_out, int out_size, void* d_ws, size_t ws_size,
                              hipStream_t stream) {
    const float* x       = (const float*)d_in[0];
    const float* weights = (const float*)d_in[1];
    const float* Wbank   = (const float*)d_in[2];
    const float* bbank   = (const float*)d_in[3];
    float* out = (float*)d_out;

    short* aggw = (short*)d_ws;                          // 1,179,648 B
    float* aggb = (float*)((char*)d_ws + 1179648);       //     4,096 B

    prep_kernel<<<dim3((NB * ASTR) / 256), dim3(256), 0, stream>>>(weights, Wbank, bbank, aggw, aggb);
    conv_kernel<<<dim3(512), dim3(512), 0, stream>>>(x, aggw, aggb, out);
}

// Round 9
// 77.613 us; speedup vs baseline: 1.1758x; 1.1758x over previous
//
#include <hip/hip_runtime.h>
#include <hip/hip_bf16.h>

// Dynamic conv2d: B=16, C_in=64, H=W=128, C_out=64, K=5, ks=3, pad=1.
// R9 = R6 (A-in-registers streaming GEMM, 32x32x16) with 2 output rows per
// barrier step (halves per-step stall overhead), 6-slot ring, raw s_barrier
// (lgkmcnt-only: stores stay in flight). Single pv[16] reused for both
// staged rows -> no extra register liveness (the R5/R7/R8 spill killer).

typedef __attribute__((ext_vector_type(8))) __bf16 bf16x8;
typedef __attribute__((ext_vector_type(16))) float f32x16;
typedef __attribute__((ext_vector_type(4))) unsigned int u32x4;

#define NB 16
#define CI 64
#define CO 64
#define HH 128
#define WW 128
#define KBANK 5
#define ASTR 36864            // shorts of aggw per b: 2m * 36ks * 2g * 32co5 * 8j

__device__ __forceinline__ unsigned short f2bfu(float f) {
    __hip_bfloat16 h = __float2bfloat16(f);
    unsigned short s;
    __builtin_memcpy(&s, &h, 2);
    return s;
}

// ---------------- kernel 1: aggregate weights + bias ----------------
// aggw per b: [m(2)][ks(36)][g(2)][co5(32)][j(8)]; k = ks*16+g*8+j,
// tap = k>>6, ci = k&63, co = m*32+co5. Wave A-load = contiguous 1KB.
__global__ void prep_kernel(const float* __restrict__ weights,
                            const float* __restrict__ Wbank,
                            const float* __restrict__ bbank,
                            short* __restrict__ aggw,
                            float* __restrict__ aggb) {
    int idx = blockIdx.x * 256 + threadIdx.x;          // < 16*36864
    int b   = idx / ASTR;
    int rem = idx - b * ASTR;
    int j   = rem & 7;
    int co5 = (rem >> 3) & 31;
    int g   = (rem >> 8) & 1;
    int mk  = rem >> 9;
    int m   = mk / 36;
    int ks  = mk - m * 36;
    int co  = m * 32 + co5;
    int k   = ks * 16 + g * 8 + j;
    int tap = k >> 6;
    int ci  = k & 63;
    float s = 0.f;
#pragma unroll
    for (int kk = 0; kk < KBANK; ++kk)
        s += weights[b * KBANK + kk] * Wbank[((kk * CO + co) * CI + ci) * 9 + tap];
    aggw[idx] = (short)f2bfu(s);
    if (k == 0) {
        float sb = 0.f;
#pragma unroll
        for (int kk = 0; kk < KBANK; ++kk)
            sb += weights[b * KBANK + kk] * bbank[kk * CO + co];
        aggb[b * CO + co] = sb;
    }
}

// ---------------- kernel 2: streaming conv ----------------
// ring[slot 6][ch 8][pix 130][8 shorts]; ch = ci>>3; pix = input w + 1.
// slot(r) = (r - r0 + 1) mod 6.
__device__ __forceinline__ void load16(const float* __restrict__ xb, int r,
                                       int sw, int scg, float (&pv)[16]) {
#pragma unroll
    for (int i = 0; i < 16; ++i)
        pv[i] = xb[((size_t)(scg * 16 + i) * HH + r) * WW + sw];
}

__device__ __forceinline__ void zero16(float (&pv)[16]) {
#pragma unroll
    for (int i = 0; i < 16; ++i) pv[i] = 0.f;
}

__device__ __forceinline__ void write16(short* __restrict__ slot, int sw, int scg,
                                        const float (&pv)[16]) {
#pragma unroll
    for (int h = 0; h < 2; ++h) {
        unsigned u0 = (unsigned)f2bfu(pv[h * 8 + 0]) | ((unsigned)f2bfu(pv[h * 8 + 1]) << 16);
        unsigned u1 = (unsigned)f2bfu(pv[h * 8 + 2]) | ((unsigned)f2bfu(pv[h * 8 + 3]) << 16);
        unsigned u2 = (unsigned)f2bfu(pv[h * 8 + 4]) | ((unsigned)f2bfu(pv[h * 8 + 5]) << 16);
        unsigned u3 = (unsigned)f2bfu(pv[h * 8 + 6]) | ((unsigned)f2bfu(pv[h * 8 + 7]) << 16);
        *(u32x4*)&slot[((scg * 2 + h) * 130 + sw + 1) * 8] = u32x4{u0, u1, u2, u3};
    }
}

__global__ __launch_bounds__(512, 2) void conv_kernel(const float* __restrict__ x,
                                                      const short* __restrict__ aggw,
                                                      const float* __restrict__ aggb,
                                                      float* __restrict__ out) {
    __shared__ short ring[6][8][130][8];               // 99,840 B (1 block/CU)

    const int t   = threadIdx.x;
    const int lin = blockIdx.x;                        // 256 blocks
    const int b     = (lin & 7) * 2 + ((lin >> 3) & 1);
    const int strip = lin >> 4;                        // 0..15
    const int r0    = strip * 8;

    const int l  = t & 63;
    const int wv = t >> 6;         // 0..7
    const int m  = wv >> 2;        // co half
    const int nq = wv & 3;         // pix quarter
    const int lm = l & 31;
    const int g  = l >> 5;

    const int sw  = t & 127;       // staging: w
    const int scg = t >> 7;        // staging: 16-ci group

    const float* xb = x + (size_t)b * CI * HH * WW;
    const short* Ab = aggw + (size_t)b * ASTR + (size_t)m * 36 * 512;

    // A-half into registers (36 x bf16x8), coalesced 1KB/wave loads
    bf16x8 A[36];
#pragma unroll
    for (int ks = 0; ks < 36; ++ks)
        A[ks] = *(const bf16x8*)(Ab + ks * 512 + l * 8);

    float bias[16];
#pragma unroll
    for (int rg = 0; rg < 16; ++rg)
        bias[rg] = aggb[b * CO + m * 32 + (rg & 3) + 8 * (rg >> 2) + 4 * g];

    // zero pix-halo (pix 0 and 129) of all 6 slots
    if (t < 96) {
        int slot = t >> 4, ch = (t >> 1) & 7, px = (t & 1) * 129;
        *(u32x4*)&ring[slot][ch][px][0] = u32x4{0u, 0u, 0u, 0u};
    }

    // prologue: rows r0-1..r0+2 -> slots 0..3 (two overlapped rounds)
    {
        float q[16], pv[16];
        if (r0 >= 1) load16(xb, r0 - 1, sw, scg, q);
        else zero16(q);
        load16(xb, r0, sw, scg, pv);
        write16(&ring[0][0][0][0], sw, scg, q);
        write16(&ring[1][0][0][0], sw, scg, pv);
        load16(xb, r0 + 1, sw, scg, q);
        load16(xb, r0 + 2, sw, scg, pv);
        write16(&ring[2][0][0][0], sw, scg, q);
        write16(&ring[3][0][0][0], sw, scg, pv);
    }
    asm volatile("s_waitcnt lgkmcnt(0)" ::: "memory");
    __builtin_amdgcn_s_barrier();
    __builtin_amdgcn_sched_barrier(0);

    // 4 steps x 2 rows
#pragma unroll
    for (int s = 0; s < 4; ++s) {
        const int r = r0 + 2 * s;
        float pv[16];

        // ---- staged row A (r+3) : load at step start
        if (r + 3 < 128) load16(xb, r + 3, sw, scg, pv);
        else zero16(pv);

        // ---- acc0: output row r (input rows r-1..r+1 = slots 2s..2s+2)
        f32x16 acc0 = (f32x16)0.0f;
#pragma unroll
        for (int ks = 0; ks < 36; ++ks) {
            const int tap = ks >> 2, q = ks & 3;
            const int dy = tap / 3, dx = tap - dy * 3;
            const short* sb = &ring[(2 * s + dy) % 6][0][0][0];
            const int pix = nq * 32 + dx + lm;
            bf16x8 bv = *(const bf16x8*)&sb[((q * 2 + g) * 130 + pix) * 8];
            acc0 = __builtin_amdgcn_mfma_f32_32x32x16_bf16(A[ks], bv, acc0, 0, 0, 0);
        }

        write16(&ring[(2 * s + 4) % 6][0][0][0], sw, scg, pv);  // waits pv-A (covered by acc0)

        // ---- staged row B (r+4)
        if (r + 4 < 128) load16(xb, r + 4, sw, scg, pv);
        else zero16(pv);

        // ---- acc1: output row r+1 (input rows r..r+2 = slots 2s+1..2s+3)
        f32x16 acc1 = (f32x16)0.0f;
#pragma unroll
        for (int ks = 0; ks < 36; ++ks) {
            const int tap = ks >> 2, q = ks & 3;
            const int dy = tap / 3, dx = tap - dy * 3;
            const short* sb = &ring[(2 * s + 1 + dy) % 6][0][0][0];
            const int pix = nq * 32 + dx + lm;
            bf16x8 bv = *(const bf16x8*)&sb[((q * 2 + g) * 130 + pix) * 8];
            acc1 = __builtin_amdgcn_mfma_f32_32x32x16_bf16(A[ks], bv, acc1, 0, 0, 0);
        }

        write16(&ring[(2 * s + 5) % 6][0][0][0], sw, scg, pv);  // waits pv-B (covered by acc1)

        // ---- output stores (stay in flight across the barrier)
        const int wc = nq * 32 + lm;
#pragma unroll
        for (int rg = 0; rg < 16; ++rg) {
            int co = m * 32 + (rg & 3) + 8 * (rg >> 2) + 4 * g;
            out[(((size_t)b * CO + co) * HH + r) * WW + wc] = acc0[rg] + bias[rg];
        }
#pragma unroll
        for (int rg = 0; rg < 16; ++rg) {
            int co = m * 32 + (rg & 3) + 8 * (rg >> 2) + 4 * g;
            out[(((size_t)b * CO + co) * HH + (r + 1)) * WW + wc] = acc1[rg] + bias[rg];
        }

        asm volatile("s_waitcnt lgkmcnt(0)" ::: "memory");
        __builtin_amdgcn_s_barrier();
        __builtin_amdgcn_sched_barrier(0);
    }
}

extern "C" void kernel_launch(void* const* d_in, const int* in_sizes, int n_in,
                              void* d_out, int out_size, void* d_ws, size_t ws_size,
                              hipStream_t stream) {
    const float* x       = (const float*)d_in[0];
    const float* weights = (const float*)d_in[1];
    const float* Wbank   = (const float*)d_in[2];
    const float* bbank   = (const float*)d_in[3];
    float* out = (float*)d_out;

    short* aggw = (short*)d_ws;                          // 1,179,648 B
    float* aggb = (float*)((char*)d_ws + 1179648);       //     4,096 B

    prep_kernel<<<dim3((NB * ASTR) / 256), dim3(256), 0, stream>>>(weights, Wbank, bbank, aggw, aggb);
    conv_kernel<<<dim3(256), dim3(512), 0, stream>>>(x, aggw, aggb, out);
}

// Round 10
// 40.239 us; speedup vs baseline: 2.2679x; 1.9288x over previous
//
#include <hip/hip_runtime.h>
#include <hip/hip_bf16.h>

// Dynamic conv2d: B=16, C_in=64, H=W=128, C_out=64, K=5, ks=3, pad=1.
// R10: register-free staging. fp32 x rows stream via global_load_lds into a
// 2-slot fp32 LDS ring; an LDS->LDS convert phase produces the bf16 ring the
// MFMA loop reads. Counted vmcnt(16) before each barrier keeps stores and
// next-row loads in flight; no HBM-latency wait in the critical path.
// A (aggregated weights) in registers as in R6. ~200 regs @ 2 waves/SIMD.

typedef __attribute__((ext_vector_type(8))) __bf16 bf16x8;
typedef __attribute__((ext_vector_type(16))) float f32x16;
typedef __attribute__((ext_vector_type(4))) unsigned int u32x4;

#define NB 16
#define CI 64
#define CO 64
#define HH 128
#define WW 128
#define KBANK 5
#define ASTR 36864            // shorts of aggw per b: 2m * 36ks * 2g * 32co5 * 8j

__device__ __forceinline__ unsigned short f2bfu(float f) {
    __hip_bfloat16 h = __float2bfloat16(f);
    unsigned short s;
    __builtin_memcpy(&s, &h, 2);
    return s;
}

// ---------------- kernel 1: aggregate weights + bias ----------------
// aggw per b: [m(2)][ks(36)][g(2)][co5(32)][j(8)]; k = ks*16+g*8+j,
// tap = k>>6, ci = k&63, co = m*32+co5. Wave A-load = contiguous 1KB.
__global__ void prep_kernel(const float* __restrict__ weights,
                            const float* __restrict__ Wbank,
                            const float* __restrict__ bbank,
                            short* __restrict__ aggw,
                            float* __restrict__ aggb) {
    int idx = blockIdx.x * 256 + threadIdx.x;          // < 16*36864
    int b   = idx / ASTR;
    int rem = idx - b * ASTR;
    int j   = rem & 7;
    int co5 = (rem >> 3) & 31;
    int g   = (rem >> 8) & 1;
    int mk  = rem >> 9;
    int m   = mk / 36;
    int ks  = mk - m * 36;
    int co  = m * 32 + co5;
    int k   = ks * 16 + g * 8 + j;
    int tap = k >> 6;
    int ci  = k & 63;
    float s = 0.f;
#pragma unroll
    for (int kk = 0; kk < KBANK; ++kk)
        s += weights[b * KBANK + kk] * Wbank[((kk * CO + co) * CI + ci) * 9 + tap];
    aggw[idx] = (short)f2bfu(s);
    if (k == 0) {
        float sb = 0.f;
#pragma unroll
        for (int kk = 0; kk < KBANK; ++kk)
            sb += weights[b * KBANK + kk] * bbank[kk * CO + co];
        aggb[b * CO + co] = sb;
    }
}

// ---------------- kernel 2: streaming conv ----------------
#define WAITV(N) asm volatile("s_waitcnt vmcnt(" #N ")" ::: "memory")
#define WAITL0   asm volatile("s_waitcnt lgkmcnt(0)" ::: "memory")
#define SBAR     do { __builtin_amdgcn_s_barrier(); __builtin_amdgcn_sched_barrier(0); } while (0)

__global__ __launch_bounds__(512, 2) void conv_kernel(const float* __restrict__ x,
                                                      const short* __restrict__ aggw,
                                                      const float* __restrict__ aggb,
                                                      float* __restrict__ out) {
    __shared__ short bring[4][8][130][8];              // bf16 ring, 66,560 B
    __shared__ float fring[2][64][128];                // fp32 ring, 65,536 B

    const int t   = threadIdx.x;
    const int lin = blockIdx.x;                        // 256 blocks
    const int b   = (lin & 7) * 2 + ((lin >> 3) & 1);  // same-b blocks share an XCD
    const int r0  = (lin >> 4) * 8;                    // 8-row strip

    const int l  = t & 63;
    const int wv = t >> 6;         // 0..7
    const int m  = wv >> 2;        // co half
    const int nq = wv & 3;         // pix quarter
    const int lm = l & 31;
    const int g  = l >> 5;

    const float* xb = x + (size_t)b * CI * HH * WW;
    const short* Ab = aggw + (size_t)b * ASTR + (size_t)m * 36 * 512;

    // A-half into registers (36 x bf16x8), coalesced 1KB/wave loads
    bf16x8 A[36];
#pragma unroll
    for (int ks = 0; ks < 36; ++ks)
        A[ks] = *(const bf16x8*)(Ab + ks * 512 + l * 8);

    float bias[16];
#pragma unroll
    for (int rg = 0; rg < 16; ++rg)
        bias[rg] = aggb[b * CO + m * 32 + (rg & 3) + 8 * (rg >> 2) + 4 * g];

    // zero pix-halo (pix 0 and 129) of all 4 bf16 slots
    if (t < 64) {
        int slot = t >> 4, ch = (t >> 1) & 7, px = (t & 1) * 129;
        *(u32x4*)&bring[slot][ch][px][0] = u32x4{0u, 0u, 0u, 0u};
    }

    // stage: row r -> fp32 slot fs via global_load_lds (4 chunks/thread, 0 regs)
    auto stage = [&](int r, int fs) {
        float* fbase = &fring[fs][0][0];
#pragma unroll
        for (int i = 0; i < 4; ++i) {
            int c  = i * 512 + t;                      // chunk id, 16B each
            int ci = c >> 5;
            int w  = (c & 31) * 4;
            const float* src = xb + ((size_t)ci * HH + r) * WW + w;
            float* dst = fbase + (size_t)(i * 512 + (t & ~63)) * 4;  // wave-uniform base
            __builtin_amdgcn_global_load_lds(
                (const __attribute__((address_space(1))) void*)src,
                (__attribute__((address_space(3))) void*)dst, 16, 0, 0);
        }
    };

    // convert: fp32 slot -> bf16 ring slot bs (2 chunks/thread); zero => write 0s
    auto convertz = [&](const float* fbase, int bs, bool zero) {
#pragma unroll
        for (int k2 = 0; k2 < 2; ++k2) {
            int c   = k2 * 512 + t;
            int ch  = c >> 7;
            int pix = (c & 127) + 1;
            unsigned u0 = 0, u1 = 0, u2 = 0, u3 = 0;
            if (!zero) {
                const float* p = fbase + ch * 1024 + (pix - 1);
                u0 = (unsigned)f2bfu(p[0])   | ((unsigned)f2bfu(p[128]) << 16);
                u1 = (unsigned)f2bfu(p[256]) | ((unsigned)f2bfu(p[384]) << 16);
                u2 = (unsigned)f2bfu(p[512]) | ((unsigned)f2bfu(p[640]) << 16);
                u3 = (unsigned)f2bfu(p[768]) | ((unsigned)f2bfu(p[896]) << 16);
            }
            *(u32x4*)&bring[bs][ch][pix][0] = u32x4{u0, u1, u2, u3};
        }
    };

    // ---- prologue: bf16 rows r0-1,r0,r0+1 -> slots 0,1,2 ; fp32 r0+2 staged
    if (r0 > 0) stage(r0 - 1, 0);
    stage(r0, 1);
    WAITV(4); SBAR;                                    // everyone's r0-1 landed
    if (r0 > 0) convertz(&fring[0][0][0], 0, false);
    else        convertz(nullptr,         0, true);
    WAITL0; SBAR;                                      // slot-0 reads drained
    stage(r0 + 1, 0);
    WAITV(4); SBAR;                                    // r0 landed
    convertz(&fring[1][0][0], 1, false);
    WAITL0; SBAR;
    stage(r0 + 2, 1);
    WAITV(4); SBAR;                                    // r0+1 landed
    convertz(&fring[0][0][0], 2, false);
    WAITV(0);                                          // r0+2 landed (step 0 reads it)
    WAITL0; SBAR;

    // ---- 8 row-steps ----
#pragma unroll
    for (int s = 0; s < 8; ++s) {
        const int r = r0 + s;

        // convert row r+2 (fp32 staged last step, barrier-guaranteed complete)
        if (r + 2 <= 127) convertz(&fring[(s + 1) & 1][0][0], (s + 3) & 3, false);
        else              convertz(nullptr,                   (s + 3) & 3, true);

        // issue next row's loads (async, consumed next step)
        if (r + 3 <= 127) stage(r + 3, s & 1);

        // MFMA: output row r from bf16 slots (s, s+1, s+2)
        f32x16 acc = (f32x16)0.0f;
#pragma unroll
        for (int ks = 0; ks < 36; ++ks) {
            const int tap = ks >> 2, q = ks & 3;
            const int dy = tap / 3, dx = tap - dy * 3;
            const short* sb = &bring[(s + dy) & 3][0][0][0];
            const int pix = nq * 32 + dx + lm;
            bf16x8 bv = *(const bf16x8*)&sb[((q * 2 + g) * 130 + pix) * 8];
            acc = __builtin_amdgcn_mfma_f32_32x32x16_bf16(A[ks], bv, acc, 0, 0, 0);
        }

        // output stores (fire-and-forget; drained by NEXT step's vmcnt(16))
        const int wc = nq * 32 + lm;
#pragma unroll
        for (int rg = 0; rg < 16; ++rg) {
            int co = m * 32 + (rg & 3) + 8 * (rg >> 2) + 4 * g;
            out[(((size_t)b * CO + co) * HH + r) * WW + wc] = acc[rg] + bias[rg];
        }

        // retire own 4 gll (16 newest = this step's stores stay in flight),
        // drain LDS ops, then barrier -> next step may read everyone's stage.
        WAITV(16);
        WAITL0;
        SBAR;
    }
}

extern "C" void kernel_launch(void* const* d_in, const int* in_sizes, int n_in,
                              void* d_out, int out_size, void* d_ws, size_t ws_size,
                              hipStream_t stream) {
    const float* x       = (const float*)d_in[0];
    const float* weights = (const float*)d_in[1];
    const float* Wbank   = (const float*)d_in[2];
    const float* bbank   = (const float*)d_in[3];
    float* out = (float*)d_out;

    short* aggw = (short*)d_ws;                          // 1,179,648 B
    float* aggb = (float*)((char*)d_ws + 1179648);       //     4,096 B

    prep_kernel<<<dim3((NB * ASTR) / 256), dim3(256), 0, stream>>>(weights, Wbank, bbank, aggw, aggb);
    conv_kernel<<<dim3(256), dim3(512), 0, stream>>>(x, aggw, aggb, out);
}